// Round 10
// baseline (186.144 us; speedup 1.0000x reference)
//
#include <hip/hip_runtime.h>

// Problem constants (M, B, D = 32, 64, 8192)
#define Mh 32
#define Bh 64
#define Dh 8192

#define GT 2048           // gram tiles: 64 b x 32 kc (KCH=256)

// ---- workspace layout (float offsets) ----
#define OFF_WSY 0                       // [64][32][32] (atomic tier only)
#define OFF_WYY (64 * 1024)
#define OFF_VS  (2 * 64 * 1024)        // [64][32]     (atomic tier only)
#define OFF_VY  (OFF_VS + 64 * 32)
#define OFF_CY  (OFF_VY + 64 * 32)     // [64][32]     (atomic tier only)
#define OFF_CS  (OFF_CY + 64 * 32)
#define OFF_G   (OFF_CS + 64 * 32)
#define WS_ZERO_FLOATS OFF_CY          // atomic-tier zero region
#define OFF_PART (OFF_G + 64)          // PSY[b][kc][1024]; PYY at +PARTF
#define PARTF    (64 * 32 * 1024)
#define OFF_VPS  (OFF_PART + 2 * PARTF)  // [b][kc][32]
#define OFF_VPY  (OFF_VPS + 64 * 32 * 32)
#define WS_END   (OFF_VPY + 64 * 32 * 32)

typedef __attribute__((ext_vector_type(8)))  __bf16 bf16x8;
typedef __attribute__((ext_vector_type(16))) float  f32x16;
typedef __attribute__((address_space(1))) const unsigned int gu32;
typedef __attribute__((address_space(3))) unsigned int lu32;

__device__ __forceinline__ float dot4(const float4 a, const float4 b)
{ return a.x * b.x + a.y * b.y + a.z * b.z + a.w * b.w; }

// fp32x8 -> bf16 hi/lo split: x ~= hi + lo with |err| ~ 2^-18 |x|
__device__ __forceinline__ void split8(const float4 a, const float4 b,
                                       bf16x8& h, bf16x8& lo)
{
    const float x[8] = {a.x, a.y, a.z, a.w, b.x, b.y, b.z, b.w};
    #pragma unroll
    for (int e = 0; e < 8; ++e) {
        h[e]  = (__bf16)x[e];
        lo[e] = (__bf16)(x[e] - (float)h[e]);
    }
}

// ---------------------------------------------------------------------------
// Kernel A: gram (r5/r8-proven burst structure, [b][kc] slab layout verified
// in r8 tier-1). grid = 2048 (b = blockIdx&63, kc = blockIdx>>6), 256 thr.
// Burst 16 global_load_lds -> ONE vmcnt drain -> barrier-free MFMA loop ->
// slab epilogue (no atomics). Swizzle rule 21 (linear LDS dest, XOR(i&15)
// pre-swizzled global source, same XOR on read; PMC-verified 0 conflicts).
// Fragment map (r3-r8 harness-verified): A==B lane map, lane l = row l&31,
// 8 k at 8*(l>>5); C/D col=l&31, row=(rr&3)+8*(rr>>2)+4*(l>>5).
// NO min-waves clamp (r1: clamp->spill), NO coop (r7/r9: retired).
// ---------------------------------------------------------------------------
template <int SLAB>
__global__ __launch_bounds__(256) void gram_kernel(
    const float* __restrict__ s, const float* __restrict__ y,
    const float* __restrict__ frc, float* __restrict__ ws)
{
    __shared__ __align__(16) float sF[4][32][64];   // 32 KB
    __shared__ __align__(16) float yF[4][32][64];   // 32 KB

    const int b  = blockIdx.x & 63;
    const int ch = blockIdx.x >> 6;                 // 0..31
    const size_t k0 = (size_t)ch << 8;              // *256
    const int t = threadIdx.x;
    const int w = t >> 6, l = t & 63;

    {   // burst: 16 global_load_lds, one drain
        const int lr = l >> 4, s16 = l & 15;
        #pragma unroll
        for (int st = 0; st < 4; ++st) {
            #pragma unroll
            for (int o = 0; o < 2; ++o) {
                const int rb = (w << 3) + (o << 2);   // wave-uniform row base
                const int i  = rb + lr;
                const int g  = s16 ^ (i & 15);        // pre-swizzled granule
                const size_t go = ((size_t)i * Bh + b) * Dh + k0 + (st << 6) + (g << 2);
                __builtin_amdgcn_global_load_lds((gu32*)(s + go), (lu32*)&sF[st][rb][0], 16, 0, 0);
                __builtin_amdgcn_global_load_lds((gu32*)(y + go), (lu32*)&yF[st][rb][0], 16, 0, 0);
            }
        }
    }

    const int i0 = t >> 4, i1 = i0 + 16, k4 = t & 15;
    const float* fp = frc + (size_t)b * Dh + k0 + (k4 << 2);
    float4 fv[4];
    #pragma unroll
    for (int st = 0; st < 4; ++st) fv[st] = *(const float4*)(fp + st * 64);

    __syncthreads();                       // single burst drain

    f32x16 accSY = {}, accYY = {};
    float avs0 = 0.f, avs1 = 0.f, avy0 = 0.f, avy1 = 0.f;
    const int row = l & 31, h = l >> 5;
    const int g0 = (w << 2) + (h << 1);
    const int rx = row & 15;
    const int x0 = i0 & 15, x1 = i1 & 15;

    #pragma unroll
    for (int st = 0; st < 4; ++st) {
        const float4 sa = *(const float4*)&sF[st][row][(g0 ^ rx) << 2];
        const float4 sb = *(const float4*)&sF[st][row][((g0 + 1) ^ rx) << 2];
        const float4 ya = *(const float4*)&yF[st][row][(g0 ^ rx) << 2];
        const float4 yb = *(const float4*)&yF[st][row][((g0 + 1) ^ rx) << 2];
        bf16x8 aSH, aSL, aYH, aYL;
        split8(sa, sb, aSH, aSL);
        split8(ya, yb, aYH, aYL);
        accSY = __builtin_amdgcn_mfma_f32_32x32x16_bf16(aSH, aYH, accSY, 0, 0, 0);
        accYY = __builtin_amdgcn_mfma_f32_32x32x16_bf16(aYH, aYH, accYY, 0, 0, 0);
        accSY = __builtin_amdgcn_mfma_f32_32x32x16_bf16(aSH, aYL, accSY, 0, 0, 0);
        accYY = __builtin_amdgcn_mfma_f32_32x32x16_bf16(aYH, aYL, accYY, 0, 0, 0);
        accSY = __builtin_amdgcn_mfma_f32_32x32x16_bf16(aSL, aYH, accSY, 0, 0, 0);
        accYY = __builtin_amdgcn_mfma_f32_32x32x16_bf16(aYL, aYH, accYY, 0, 0, 0);

        const float4 s0v = *(const float4*)&sF[st][i0][(k4 ^ x0) << 2];
        const float4 y0v = *(const float4*)&yF[st][i0][(k4 ^ x0) << 2];
        const float4 s1v = *(const float4*)&sF[st][i1][(k4 ^ x1) << 2];
        const float4 y1v = *(const float4*)&yF[st][i1][(k4 ^ x1) << 2];
        const float4 f = fv[st];
        avs0 += dot4(s0v, f);  avy0 += dot4(y0v, f);
        avs1 += dot4(s1v, f);  avy1 += dot4(y1v, f);
    }

    #pragma unroll
    for (int m = 1; m < 16; m <<= 1) {
        avs0 += __shfl_xor(avs0, m);
        avs1 += __shfl_xor(avs1, m);
        avy0 += __shfl_xor(avy0, m);
        avy1 += __shfl_xor(avy1, m);
    }
    const int g16 = t & 15;
    const size_t stile = (size_t)b * 32 + ch;          // [b][kc] slab order
    if (SLAB) {
        if      (g16 == 0) ws[OFF_VPS + stile * 32 + i0] = avs0;
        else if (g16 == 1) ws[OFF_VPS + stile * 32 + i1] = avs1;
        else if (g16 == 2) ws[OFF_VPY + stile * 32 + i0] = avy0;
        else if (g16 == 3) ws[OFF_VPY + stile * 32 + i1] = avy1;
    } else {
        if      (g16 == 0) unsafeAtomicAdd(&ws[OFF_VS + b * 32 + i0], avs0);
        else if (g16 == 1) unsafeAtomicAdd(&ws[OFF_VS + b * 32 + i1], avs1);
        else if (g16 == 2) unsafeAtomicAdd(&ws[OFF_VY + b * 32 + i0], avy0);
        else if (g16 == 3) unsafeAtomicAdd(&ws[OFF_VY + b * 32 + i1], avy1);
    }

    __syncthreads();             // all sF/yF reads done before LDS reuse
    float* RS = &sF[0][0][0];
    float* RY = &yF[0][0][0];
    #pragma unroll
    for (int rr = 0; rr < 16; ++rr) {
        const int i = (rr & 3) + ((rr >> 2) << 3) + (h << 2);
        RS[w * 1024 + i * 32 + row] = accSY[rr];
        RY[w * 1024 + i * 32 + row] = accYY[rr];
    }
    __syncthreads();

    const int e4 = t << 2;
    if (SLAB) {
        float* PS = ws + OFF_PART + stile * 1024;
        float* PY = PS + PARTF;
        float4 a0 = *(const float4*)&RS[e4];
        const float4 a1 = *(const float4*)&RS[1024 + e4];
        const float4 a2 = *(const float4*)&RS[2048 + e4];
        const float4 a3 = *(const float4*)&RS[3072 + e4];
        a0.x += a1.x + a2.x + a3.x;  a0.y += a1.y + a2.y + a3.y;
        a0.z += a1.z + a2.z + a3.z;  a0.w += a1.w + a2.w + a3.w;
        *(float4*)&PS[e4] = a0;
        float4 c0 = *(const float4*)&RY[e4];
        const float4 c1 = *(const float4*)&RY[1024 + e4];
        const float4 c2 = *(const float4*)&RY[2048 + e4];
        const float4 c3 = *(const float4*)&RY[3072 + e4];
        c0.x += c1.x + c2.x + c3.x;  c0.y += c1.y + c2.y + c3.y;
        c0.z += c1.z + c2.z + c3.z;  c0.w += c1.w + c2.w + c3.w;
        *(float4*)&PY[e4] = c0;
    } else {
        float* WSY = ws + OFF_WSY + b * 1024;
        float* WYY = ws + OFF_WYY + b * 1024;
        for (int e = t; e < 1024; e += 256) {
            unsafeAtomicAdd(&WSY[e], RS[e] + RS[1024 + e] + RS[2048 + e] + RS[3072 + e]);
            unsafeAtomicAdd(&WYY[e], RY[e] + RY[1024 + e] + RY[2048 + e] + RY[3072 + e]);
        }
    }
}

// ---------------------------------------------------------------------------
// Kernel B (2-dispatch path): combine with REDUNDANT per-block recursion.
// grid = 512 (b = blockIdx&63, ch = blockIdx>>6), 1024 threads.
// Prologue: 1024 threads reduce this b's [b][kc]-contiguous slab (256 KB,
// L3-hot from gram) into LDS; wave 0 runs the f64 scans (code verified
// correct in r7's passing run); results stay in LDS. Deterministic => all
// 8 blocks of a b agree bit-exactly. Then the streaming combine.
// Eliminates the recur dispatch + its gap; no coop, no atomics, no memset.
// ---------------------------------------------------------------------------
__global__ __launch_bounds__(1024) void comb2_kernel(
    const float* __restrict__ s, const float* __restrict__ y,
    const float* __restrict__ frc, const float* __restrict__ ws,
    float* __restrict__ out)
{
    __shared__ float WSY_l[1024], WYY_l[1024];
    __shared__ float vsL[32], vyL[32], cyL[32], csL[32];
    __shared__ float gS;
    __shared__ float4 red[3][256];

    const int b  = blockIdx.x & 63;
    const int ch = blockIdx.x >> 6;
    const int t  = threadIdx.x;

    // ---- Phase A: redundant recursion for this b ----
    if (t < 256) {                          // Wsy reduce (coalesced, L3-hot)
        const int e4 = t << 2;
        const float* PS = ws + OFF_PART + (size_t)b * 32 * 1024;
        float4 a = make_float4(0.f, 0.f, 0.f, 0.f);
        #pragma unroll 8
        for (int kc = 0; kc < 32; ++kc) {
            const float4 v = *(const float4*)&PS[kc * 1024 + e4];
            a.x += v.x; a.y += v.y; a.z += v.z; a.w += v.w;
        }
        *(float4*)&WSY_l[e4] = a;
    } else if (t < 512) {                   // Wyy reduce
        const int e4 = (t - 256) << 2;
        const float* PY = ws + OFF_PART + PARTF + (size_t)b * 32 * 1024;
        float4 c = make_float4(0.f, 0.f, 0.f, 0.f);
        #pragma unroll 8
        for (int kc = 0; kc < 32; ++kc) {
            const float4 u = *(const float4*)&PY[kc * 1024 + e4];
            c.x += u.x; c.y += u.y; c.z += u.z; c.w += u.w;
        }
        *(float4*)&WYY_l[e4] = c;
    } else if (t < 576) {                   // vs (512-543) / vy (544-575)
        const int i = t & 31;
        const float* PV = ws + (t < 544 ? OFF_VPS : OFF_VPY) + (size_t)b * 32 * 32;
        float acc = 0.f;
        #pragma unroll 8
        for (int kc = 0; kc < 32; ++kc) acc += PV[kc * 32 + i];
        (t < 544 ? vsL : vyL)[i] = acc;
    }
    __syncthreads();

    if (t < 64) {                           // f64 scans (r7-verified, LDS-read)
        const int i = t & 31;               // lanes 32..63 mirror (writes guarded)
        const double r = 1.0 / (double)WSY_l[i * 32 + i];
        double acc2 = -(double)vsL[i];
        double a_val = 0.0;
        #pragma unroll
        for (int j = 31; j >= 0; --j) {     // backward scan
            const double aj = __shfl(r, j) * __shfl(acc2, j);
            if (i == j) a_val = aj;
            if (i < j)  acc2 -= aj * (double)WSY_l[i * 32 + j];
        }
        const double g = (double)WSY_l[31 * 32 + 31] / (double)WYY_l[31 * 32 + 31];
        double u = -(double)vyL[i];
        #pragma unroll
        for (int j = 0; j < 32; ++j)
            u -= __shfl(a_val, j) * (double)WYY_l[i * 32 + j];
        u *= g;
        double tt2 = u;
        double b_val = 0.0;
        #pragma unroll
        for (int j = 0; j < 32; ++j) {      // forward scan
            const double bj = __shfl(r, j) * __shfl(tt2, j);
            if (i == j) b_val = bj;
            const double dj = __shfl(a_val, j) - bj;
            if (i > j) tt2 += dj * (double)WSY_l[j * 32 + i];
        }
        if (t < 32) {
            cyL[i] = (float)(g * a_val);
            csL[i] = (float)(b_val - a_val);
        }
        if (t == 0) gS = (float)g;
    }
    __syncthreads();

    // ---- Phase B: streaming combine (r5-proven 4-way i-split) ----
    const int q  = t >> 8;                  // quarter 0..3: i in [8q, 8q+8)
    const int tt = t & 255;
    const int d  = (ch << 10) + (tt << 2);
    float4 acc = make_float4(0.f, 0.f, 0.f, 0.f);
    if (q == 0) {
        const float g = gS;
        const float4 fv = *(const float4*)(frc + (size_t)b * Dh + d);
        acc.x = g * fv.x; acc.y = g * fv.y; acc.z = g * fv.z; acc.w = g * fv.w;
    }
    const int ib = q << 3;
    #pragma unroll
    for (int i2 = 0; i2 < 8; ++i2) {
        const int i = ib + i2;
        const float4 yv = *(const float4*)(y + ((size_t)i * Bh + b) * Dh + d);
        const float4 sv = *(const float4*)(s + ((size_t)i * Bh + b) * Dh + d);
        const float a1 = cyL[i], a2 = csL[i];
        acc.x += a1 * yv.x + a2 * sv.x;
        acc.y += a1 * yv.y + a2 * sv.y;
        acc.z += a1 * yv.z + a2 * sv.z;
        acc.w += a1 * yv.w + a2 * sv.w;
    }
    if (q) red[q - 1][tt] = acc;
    __syncthreads();
    if (q == 0) {
        const float4 r0 = red[0][tt], r1 = red[1][tt], r2 = red[2][tt];
        acc.x += r0.x + r1.x + r2.x;
        acc.y += r0.y + r1.y + r2.y;
        acc.z += r0.z + r1.z + r2.z;
        acc.w += r0.w + r1.w + r2.w;
        *(float4*)(out + (size_t)b * Dh + d) = acc;
    }
}

// ---------------------------------------------------------------------------
// Atomic-tier fallback (ws too small for slabs): r3-style recur + combine.
// ---------------------------------------------------------------------------
__global__ __launch_bounds__(64) void recur_fb(float* __restrict__ ws)
{
    const int b    = blockIdx.x;
    const int lane = threadIdx.x;
    const int i    = lane & 31;

    const float* WSY = ws + OFF_WSY + b * 1024;
    const float* WYY = ws + OFF_WYY + b * 1024;

    float row_sy[32], col_sy[32], row_yy[32];
    #pragma unroll
    for (int j = 0; j < 32; ++j) {
        row_sy[j] = WSY[i * 32 + j];
        col_sy[j] = WSY[j * 32 + i];
        row_yy[j] = WYY[i * 32 + j];
    }

    const double r = 1.0 / (double)row_sy[i];
    double acc = -(double)ws[OFF_VS + b * 32 + i];
    double a_val = 0.0;
    #pragma unroll
    for (int j = 31; j >= 0; --j) {
        const double aj = __shfl(r, j) * __shfl(acc, j);
        if (i == j) a_val = aj;
        if (i < j)  acc -= aj * (double)row_sy[j];
    }
    const double g = (double)WSY[31 * 32 + 31] / (double)WYY[31 * 32 + 31];
    double u = -(double)ws[OFF_VY + b * 32 + i];
    #pragma unroll
    for (int j = 0; j < 32; ++j)
        u -= __shfl(a_val, j) * (double)row_yy[j];
    u *= g;
    double tt = u;
    double b_val = 0.0;
    #pragma unroll
    for (int j = 0; j < 32; ++j) {
        const double bj = __shfl(r, j) * __shfl(tt, j);
        if (i == j) b_val = bj;
        const double dj = __shfl(a_val, j) - bj;
        if (i > j) tt += dj * (double)col_sy[j];
    }
    if (lane < 32) {
        ws[OFF_CY + b * 32 + i] = (float)(g * a_val);
        ws[OFF_CS + b * 32 + i] = (float)(b_val - a_val);
    }
    if (lane == 0) ws[OFF_G + b] = (float)g;
}

__global__ __launch_bounds__(1024) void combine_fb(
    const float* __restrict__ s, const float* __restrict__ y,
    const float* __restrict__ frc, const float* __restrict__ ws,
    float* __restrict__ out)
{
    __shared__ float cy[32], cs[32];
    __shared__ float4 red[3][256];
    const int b  = blockIdx.x & 63;
    const int ch = blockIdx.x >> 6;
    const int t  = threadIdx.x;
    const int q  = t >> 8;
    const int tt = t & 255;
    if (t < 32) { cy[t] = ws[OFF_CY + b * 32 + t]; cs[t] = ws[OFF_CS + b * 32 + t]; }
    __syncthreads();
    const int d = ch * 1024 + (tt << 2);
    float4 acc = make_float4(0.f, 0.f, 0.f, 0.f);
    if (q == 0) {
        const float g = ws[OFF_G + b];
        const float4 fv = *(const float4*)(frc + (size_t)b * Dh + d);
        acc.x = g * fv.x; acc.y = g * fv.y; acc.z = g * fv.z; acc.w = g * fv.w;
    }
    const int ib = q << 3;
    #pragma unroll
    for (int i2 = 0; i2 < 8; ++i2) {
        const int i = ib + i2;
        const float4 yv = *(const float4*)(y + ((size_t)i * Bh + b) * Dh + d);
        const float4 sv = *(const float4*)(s + ((size_t)i * Bh + b) * Dh + d);
        const float a1 = cy[i], a2 = cs[i];
        acc.x += a1 * yv.x + a2 * sv.x;
        acc.y += a1 * yv.y + a2 * sv.y;
        acc.z += a1 * yv.z + a2 * sv.z;
        acc.w += a1 * yv.w + a2 * sv.w;
    }
    if (q) red[q - 1][tt] = acc;
    __syncthreads();
    if (q == 0) {
        const float4 r0 = red[0][tt], r1 = red[1][tt], r2 = red[2][tt];
        acc.x += r0.x + r1.x + r2.x;
        acc.y += r0.y + r1.y + r2.y;
        acc.z += r0.z + r1.z + r2.z;
        acc.w += r0.w + r1.w + r2.w;
        *(float4*)(out + (size_t)b * Dh + d) = acc;
    }
}

extern "C" void kernel_launch(void* const* d_in, const int* in_sizes, int n_in,
                              void* d_out, int out_size, void* d_ws, size_t ws_size,
                              hipStream_t stream)
{
    const float* s   = (const float*)d_in[0];
    const float* y   = (const float*)d_in[1];
    const float* frc = (const float*)d_in[2];
    float* out = (float*)d_out;
    float* ws  = (float*)d_ws;

    if (ws_size >= (size_t)WS_END * sizeof(float)) {
        // 2-dispatch slab path: no atomics, no memset, no coop.
        gram_kernel<1><<<dim3(GT), dim3(256), 0, stream>>>(s, y, frc, ws);
        comb2_kernel<<<dim3(Bh * 8), dim3(1024), 0, stream>>>(s, y, frc, ws, out);
    } else {
        // atomic-tier fallback (3 dispatches + memset).
        hipMemsetAsync(d_ws, 0, (size_t)WS_ZERO_FLOATS * sizeof(float), stream);
        gram_kernel<0><<<dim3(GT), dim3(256), 0, stream>>>(s, y, frc, ws);
        recur_fb<<<dim3(Bh), dim3(64), 0, stream>>>(ws);
        combine_fb<<<dim3(Bh * 8), dim3(1024), 0, stream>>>(s, y, frc, ws, out);
    }
}